// Round 1
// baseline (600.282 us; speedup 1.0000x reference)
//
#include <hip/hip_runtime.h>
#include <stdint.h>

// QKVAttention encoder, MI355X (gfx950).
// One workgroup per batch-head (256 wgs x 1024 threads, 16 waves).
// Phase A: q-compress GEMM (bf16 MFMA, fp32 acc) -> qT[o][c] bf16 in LDS.
// Phase B/C: flash attention over 32 s-tiles of 32 tokens, online softmax.

namespace {

constexpr int T_ = 1024;          // origin tokens
constexpr int SB = 32;            // s-tile
constexpr int NITER = T_ / SB;    // 32
constexpr float SCALE2 = 0.08838834764831845f;  // 1/sqrt(128) = scale^2
constexpr float LOG2E  = 1.4426950408889634f;

typedef __bf16 bf16x8 __attribute__((ext_vector_type(8)));
typedef float  f32x4  __attribute__((ext_vector_type(4)));

// ---- LDS layout (bytes) ----
constexpr int QT_OFF = 0;                   // qT [256 o][128 c] bf16, row 256B, swz ((o&7)<<4)
constexpr int R2     = 65536;
constexpr int A_OFF  = R2;                  // phase A: W tile [256][64] bf16, row 128B, swz
constexpr int B_OFF  = R2 + 32768;          // phase A: Qraw tile [128][64] bf16
constexpr int KT_OFF = R2;                  // [2][32 s][128 c] bf16, row 256B, swz ((s&7)<<4)
constexpr int VT_OFF = R2 + 16384;          // [2][128 c][40 s] bf16, row 80B (pad)
constexpr int P_OFF  = R2 + 16384 + 20480;  // [256 o][40 s] bf16, row 80B
constexpr int AL_OFF = P_OFF + 20480;       // [256] f32 (alpha / lsum broadcast)
constexpr int LDS_SZ = AL_OFF + 1024;       // 123904 B

__device__ __forceinline__ unsigned short f2bf(float f) {
    unsigned int u = __builtin_bit_cast(unsigned int, f);
    u += 0x7fffu + ((u >> 16) & 1u);        // RNE
    return (unsigned short)(u >> 16);
}

__global__ __launch_bounds__(1024) void qkv_attn_kernel(
    const float* __restrict__ qkv, const float* __restrict__ wq,
    const float* __restrict__ bq, float* __restrict__ out)
{
    __shared__ alignas(16) char smem[LDS_SZ];

    const int tid  = threadIdx.x;
    const int lane = tid & 63;
    const int g    = lane >> 4;      // 16-lane group 0..3
    const int ln   = lane & 15;
    const int wv   = tid >> 6;       // wave 0..15
    const int wo   = wv << 4;        // this wave's o-chunk base (16 rows)

    const int wg = blockIdx.x;       // bH index
    const int b  = wg >> 3, h = wg & 7;
    const float* Qg = qkv + (size_t)(b * 3072 + h * 384) * T_;  // [128][1024]
    const float* Kg = Qg + 128 * T_;
    const float* Vg = Qg + 256 * T_;

    // ================= Phase A: qT[o][c] = (Qraw @ W^T + b) * scale^2 =================
    f32x4 qacc[8];
    #pragma unroll
    for (int i = 0; i < 8; ++i) qacc[i] = f32x4{0.f, 0.f, 0.f, 0.f};

    for (int kt = 0; kt < 16; ++kt) {
        const int t0 = kt << 6;
        __syncthreads();
        // stage W tile 256x64 (4 float4 / thread)
        #pragma unroll
        for (int j = 0; j < 4; ++j) {
            int i = tid + (j << 10);
            int row = i >> 4, t4 = i & 15;
            float4 v = *(const float4*)(wq + row * T_ + t0 + (t4 << 2));
            ushort4 hv = make_ushort4(f2bf(v.x), f2bf(v.y), f2bf(v.z), f2bf(v.w));
            *(ushort4*)(smem + A_OFF + (((row << 7) + (t4 << 3)) ^ ((row & 7) << 4))) = hv;
        }
        // stage Qraw tile 128x64 (2 float4 / thread)
        #pragma unroll
        for (int j = 0; j < 2; ++j) {
            int i = tid + (j << 10);
            int row = i >> 4, t4 = i & 15;
            float4 v = *(const float4*)(Qg + row * T_ + t0 + (t4 << 2));
            ushort4 hv = make_ushort4(f2bf(v.x), f2bf(v.y), f2bf(v.z), f2bf(v.w));
            *(ushort4*)(smem + B_OFF + (((row << 7) + (t4 << 3)) ^ ((row & 7) << 4))) = hv;
        }
        __syncthreads();
        #pragma unroll
        for (int kk = 0; kk < 2; ++kk) {
            int arow = wo + ln;
            bf16x8 af = *(const bf16x8*)(smem + A_OFF +
                (((arow << 7) + (kk << 6) + (g << 4)) ^ ((arow & 7) << 4)));
            #pragma unroll
            for (int ct = 0; ct < 8; ++ct) {
                int brow = (ct << 4) + ln;
                bf16x8 bfr = *(const bf16x8*)(smem + B_OFF +
                    (((brow << 7) + (kk << 6) + (g << 4)) ^ ((brow & 7) << 4)));
                qacc[ct] = __builtin_amdgcn_mfma_f32_16x16x32_bf16(af, bfr, qacc[ct], 0, 0, 0);
            }
        }
    }
    // epilogue A: bias + scale^2, write qT bf16 (wave-private rows wo..wo+15)
    {
        float bqv[4];
        #pragma unroll
        for (int r = 0; r < 4; ++r) bqv[r] = bq[wo + (g << 2) + r];
        #pragma unroll
        for (int ct = 0; ct < 8; ++ct) {
            #pragma unroll
            for (int r = 0; r < 4; ++r) {
                int o = wo + (g << 2) + r;
                int c = (ct << 4) + ln;
                float qv = (qacc[ct][r] + bqv[r]) * SCALE2;
                *(unsigned short*)(smem + QT_OFF +
                    (((o << 8) + (c << 1)) ^ ((o & 7) << 4))) = f2bf(qv);
            }
        }
    }

    __syncthreads();   // phase A reads of lds_a/lds_b done everywhere before K/V staging

    // ================= Phase B/C: flash attention =================
    float m_run[4], l_run[4];
    #pragma unroll
    for (int r = 0; r < 4; ++r) { m_run[r] = -1e30f; l_run[r] = 0.f; }
    f32x4 acc[8];
    #pragma unroll
    for (int i = 0; i < 8; ++i) acc[i] = f32x4{0.f, 0.f, 0.f, 0.f};

    const int sc = tid >> 3;       // 0..127 (c row for staging)
    const int s4 = tid & 7;        // float4 index along s
    const float* Krow = Kg + sc * T_ + (s4 << 2);
    const float* Vrow = Vg + sc * T_ + (s4 << 2);

    // prologue: stage s-tile 0 into buffer 0
    {
        float4 kv = *(const float4*)(Krow);
        #pragma unroll
        for (int j = 0; j < 4; ++j) {
            int srow = (s4 << 2) + j;
            *(unsigned short*)(smem + KT_OFF +
                (((srow << 8) + (sc << 1)) ^ ((srow & 7) << 4))) = f2bf((&kv.x)[j]);
        }
        float4 vv = *(const float4*)(Vrow);
        ushort4 hv = make_ushort4(f2bf(vv.x), f2bf(vv.y), f2bf(vv.z), f2bf(vv.w));
        *(ushort4*)(smem + VT_OFF + sc * 80 + (s4 << 3)) = hv;
    }

    for (int it = 0; it < NITER; ++it) {
        __syncthreads();           // stage(it) visible; all compute(it-1) done
        const int cur = it & 1;
        if (it + 1 < NITER) {      // stage next tile into other buffer
            const int nb = cur ^ 1;
            const int s0 = (it + 1) << 5;
            float4 kv = *(const float4*)(Krow + s0);
            #pragma unroll
            for (int j = 0; j < 4; ++j) {
                int srow = (s4 << 2) + j;
                *(unsigned short*)(smem + KT_OFF + (nb << 13) +
                    (((srow << 8) + (sc << 1)) ^ ((srow & 7) << 4))) = f2bf((&kv.x)[j]);
            }
            float4 vv = *(const float4*)(Vrow + s0);
            ushort4 hv = make_ushort4(f2bf(vv.x), f2bf(vv.y), f2bf(vv.z), f2bf(vv.w));
            *(ushort4*)(smem + VT_OFF + nb * 10240 + sc * 80 + (s4 << 3)) = hv;
        }

        // logits[o=wo+4g+r][s=sn*16+ln] = sum_c qT[o][c] * K[c][s]
        f32x4 L[2];
        L[0] = f32x4{0.f, 0.f, 0.f, 0.f};
        L[1] = f32x4{0.f, 0.f, 0.f, 0.f};
        #pragma unroll
        for (int kk = 0; kk < 4; ++kk) {
            int orow = wo + ln;
            bf16x8 af = *(const bf16x8*)(smem + QT_OFF +
                (((orow << 8) + (kk << 6) + (g << 4)) ^ ((orow & 7) << 4)));
            #pragma unroll
            for (int sn = 0; sn < 2; ++sn) {
                int srow = (sn << 4) + ln;
                bf16x8 bfr = *(const bf16x8*)(smem + KT_OFF + (cur << 13) +
                    (((srow << 8) + (kk << 6) + (g << 4)) ^ ((srow & 7) << 4)));
                L[sn] = __builtin_amdgcn_mfma_f32_16x16x32_bf16(af, bfr, L[sn], 0, 0, 0);
            }
        }

        // online softmax (per o-row; 16-lane butterfly over s)
        float alpha;
        {
            float al[4];
            #pragma unroll
            for (int r = 0; r < 4; ++r) {
                float mx = fmaxf(L[0][r], L[1][r]);
                #pragma unroll
                for (int w = 1; w < 16; w <<= 1) mx = fmaxf(mx, __shfl_xor(mx, w, 64));
                float mnew = fmaxf(m_run[r], mx);
                float a0 = exp2f((m_run[r] - mnew) * LOG2E);
                float p0 = exp2f((L[0][r] - mnew) * LOG2E);
                float p1 = exp2f((L[1][r] - mnew) * LOG2E);
                float ts = p0 + p1;
                #pragma unroll
                for (int w = 1; w < 16; w <<= 1) ts += __shfl_xor(ts, w, 64);
                l_run[r] = l_run[r] * a0 + ts;
                m_run[r] = mnew;
                al[r] = a0;
                int o = wo + (g << 2) + r;
                *(unsigned short*)(smem + P_OFF + o * 80 + (ln << 1))      = f2bf(p0);
                *(unsigned short*)(smem + P_OFF + o * 80 + 32 + (ln << 1)) = f2bf(p1);
            }
            if (ln == 0) {
                float* alp = (float*)(smem + AL_OFF);
                #pragma unroll
                for (int r = 0; r < 4; ++r) alp[wo + (g << 2) + r] = al[r];
            }
            alpha = ((const float*)(smem + AL_OFF))[wo + ln];
        }

        // rescale accumulators, then acc[c][o] += V[c][s] * P[o][s]
        #pragma unroll
        for (int mt = 0; mt < 8; ++mt) {
            acc[mt][0] *= alpha; acc[mt][1] *= alpha;
            acc[mt][2] *= alpha; acc[mt][3] *= alpha;
        }
        bf16x8 pf = *(const bf16x8*)(smem + P_OFF + (wo + ln) * 80 + (g << 4));
        #pragma unroll
        for (int mt = 0; mt < 8; ++mt) {
            int crow = (mt << 4) + ln;
            bf16x8 vf = *(const bf16x8*)(smem + VT_OFF + cur * 10240 + crow * 80 + (g << 4));
            acc[mt] = __builtin_amdgcn_mfma_f32_16x16x32_bf16(vf, pf, acc[mt], 0, 0, 0);
        }
    }

    // ================= epilogue: out[b][h*128+c][o] = acc / l =================
    {
        if (ln == 0) {
            float* alp = (float*)(smem + AL_OFF);
            #pragma unroll
            for (int r = 0; r < 4; ++r) alp[wo + (g << 2) + r] = l_run[r];
        }
        float linv = 1.0f / ((const float*)(smem + AL_OFF))[wo + ln];
        float* ob = out + (size_t)(b * 1024 + h * 128) * 256 + wo + ln;
        #pragma unroll
        for (int mt = 0; mt < 8; ++mt) {
            #pragma unroll
            for (int r = 0; r < 4; ++r) {
                int c = (mt << 4) + (g << 2) + r;
                ob[(size_t)c * 256] = acc[mt][r] * linv;
            }
        }
    }
}

} // namespace

extern "C" void kernel_launch(void* const* d_in, const int* in_sizes, int n_in,
                              void* d_out, int out_size, void* d_ws, size_t ws_size,
                              hipStream_t stream) {
    const float* qkv = (const float*)d_in[0];
    const float* wq  = (const float*)d_in[1];
    const float* bq  = (const float*)d_in[2];
    float* out = (float*)d_out;
    hipLaunchKernelGGL(qkv_attn_kernel, dim3(256), dim3(1024), 0, stream,
                       qkv, wq, bq, out);
}

// Round 2
// 595.247 us; speedup vs baseline: 1.0085x; 1.0085x over previous
//
#include <hip/hip_runtime.h>
#include <stdint.h>

// QKVAttention encoder, MI355X (gfx950), v2.
// 256 wgs (one per batch-head) x 512 threads (8 waves; VGPR cap 256 -> no spills).
// Phase A: q-compress GEMM (bf16 MFMA) -> qT[o=256][c=128] bf16 in LDS.
// Phase B: flash attention, 32 s-tiles of 32. Swapped QK^T (D[m=s][n=o]) so the
// softmax reduce is per-lane + 2 shfl_xor, and alpha/l are lane-aligned with acc.

namespace {

constexpr int T_ = 1024;
constexpr int NITER = 32;                         // 1024 / 32
constexpr float SCALE2 = 0.08838834764831845f;    // 1/sqrt(128)
constexpr float LOG2E  = 1.4426950408889634f;

typedef __bf16 bf16x8 __attribute__((ext_vector_type(8)));
typedef float  f32x4  __attribute__((ext_vector_type(4)));

// ---- LDS layout (bytes) ----
constexpr int QT_OFF = 0;                    // qT [256 o][128 c] bf16, row 256B, swz ((o&7)<<4)
constexpr int R2     = 65536;
constexpr int A_OFF  = R2;                   // phase A: W tile [256][64] bf16, row 128B, swz
constexpr int B_OFF  = R2 + 32768;           // phase A: Qraw tile [128][64] bf16
constexpr int KT_OFF = R2;                   // [2][32 s][128 c] bf16, row 256B, swz ((s&7)<<4)
constexpr int VT_OFF = R2 + 16384;           // [2][128 c][40 s] bf16, row 80B (pad)
constexpr int P_OFF  = VT_OFF + 20480;       // [256 o][40 s] bf16, row 80B
constexpr int LDS_SZ = P_OFF + 20480;        // 122880 B

__device__ __forceinline__ unsigned short f2bf(float f) {
    unsigned int u = __builtin_bit_cast(unsigned int, f);
    u += 0x7fffu + ((u >> 16) & 1u);         // RNE
    return (unsigned short)(u >> 16);
}

__global__ __launch_bounds__(512, 2) void qkv_attn_kernel(
    const float* __restrict__ qkv, const float* __restrict__ wq,
    const float* __restrict__ bq, float* __restrict__ out)
{
    __shared__ alignas(16) char smem[LDS_SZ];

    const int tid  = threadIdx.x;
    const int lane = tid & 63;
    const int g    = lane >> 4;      // 16-lane group 0..3 (k-slice)
    const int ln   = lane & 15;
    const int wv   = tid >> 6;       // wave 0..7
    const int wo   = wv << 5;        // wave's 32 o-rows

    const int wg = blockIdx.x;       // bH
    const int b  = wg >> 3, h = wg & 7;
    const float* Qg = qkv + (size_t)(b * 3072 + h * 384) * T_;  // [128][1024]
    const float* Kg = Qg + 128 * T_;
    const float* Vg = Qg + 256 * T_;

    // ================= Phase A: qT[o][c] = (W @ Qraw^T + b) * scale^2 =================
    f32x4 qacc[2][8];
    #pragma unroll
    for (int ot = 0; ot < 2; ++ot)
        #pragma unroll
        for (int ct = 0; ct < 8; ++ct) qacc[ot][ct] = f32x4{0.f, 0.f, 0.f, 0.f};

    for (int kt = 0; kt < 16; ++kt) {
        const int t0 = kt << 6;
        __syncthreads();
        // stage W tile 256x64 (8 float4 / thread)
        #pragma unroll
        for (int j = 0; j < 8; ++j) {
            int i = tid + (j << 9);
            int row = i >> 4, t4 = i & 15;
            float4 v = *(const float4*)(wq + row * T_ + t0 + (t4 << 2));
            ushort4 hv = make_ushort4(f2bf(v.x), f2bf(v.y), f2bf(v.z), f2bf(v.w));
            *(ushort4*)(smem + A_OFF + (((row << 7) + (t4 << 3)) ^ ((row & 7) << 4))) = hv;
        }
        // stage Qraw tile 128x64 (4 float4 / thread)
        #pragma unroll
        for (int j = 0; j < 4; ++j) {
            int i = tid + (j << 9);
            int row = i >> 4, t4 = i & 15;
            float4 v = *(const float4*)(Qg + row * T_ + t0 + (t4 << 2));
            ushort4 hv = make_ushort4(f2bf(v.x), f2bf(v.y), f2bf(v.z), f2bf(v.w));
            *(ushort4*)(smem + B_OFF + (((row << 7) + (t4 << 3)) ^ ((row & 7) << 4))) = hv;
        }
        __syncthreads();
        #pragma unroll
        for (int kk = 0; kk < 2; ++kk) {
            int a0r = wo + ln, a1r = wo + 16 + ln;
            bf16x8 af0 = *(const bf16x8*)(smem + A_OFF +
                (((a0r << 7) + (kk << 6) + (g << 4)) ^ ((a0r & 7) << 4)));
            bf16x8 af1 = *(const bf16x8*)(smem + A_OFF +
                (((a1r << 7) + (kk << 6) + (g << 4)) ^ ((a1r & 7) << 4)));
            #pragma unroll
            for (int ct = 0; ct < 8; ++ct) {
                int brow = (ct << 4) + ln;
                bf16x8 bfr = *(const bf16x8*)(smem + B_OFF +
                    (((brow << 7) + (kk << 6) + (g << 4)) ^ ((brow & 7) << 4)));
                qacc[0][ct] = __builtin_amdgcn_mfma_f32_16x16x32_bf16(af0, bfr, qacc[0][ct], 0, 0, 0);
                qacc[1][ct] = __builtin_amdgcn_mfma_f32_16x16x32_bf16(af1, bfr, qacc[1][ct], 0, 0, 0);
            }
        }
    }
    // epilogue A: bias + scale^2 -> qT bf16 (rows owned by this wave)
    #pragma unroll
    for (int ot = 0; ot < 2; ++ot) {
        #pragma unroll
        for (int r = 0; r < 4; ++r) {
            int o = wo + (ot << 4) + (g << 2) + r;
            float bv = bq[o];
            #pragma unroll
            for (int ct = 0; ct < 8; ++ct) {
                int c = (ct << 4) + ln;
                float qv = (qacc[ot][ct][r] + bv) * SCALE2;
                *(unsigned short*)(smem + QT_OFF +
                    (((o << 8) + (c << 1)) ^ ((o & 7) << 4))) = f2bf(qv);
            }
        }
    }

    __syncthreads();   // phase-A LDS reads done before K/V staging overwrites

    // ================= Phase B: flash attention =================
    float m_run[2] = {-1e30f, -1e30f};
    float l_run[2] = {0.f, 0.f};
    f32x4 acc[8][2];
    #pragma unroll
    for (int ct = 0; ct < 8; ++ct) { acc[ct][0] = f32x4{0,0,0,0}; acc[ct][1] = f32x4{0,0,0,0}; }

    const int s4 = tid & 7;

    // prologue: stage s-tile 0 into buffer 0
    #pragma unroll
    for (int j = 0; j < 2; ++j) {
        int c = (tid >> 3) + (j << 6);
        float4 kv = *(const float4*)(Kg + c * T_ + (s4 << 2));
        #pragma unroll
        for (int jj = 0; jj < 4; ++jj) {
            int srow = (s4 << 2) + jj;
            *(unsigned short*)(smem + KT_OFF +
                (((srow << 8) + (c << 1)) ^ ((srow & 7) << 4))) = f2bf((&kv.x)[jj]);
        }
        float4 vv = *(const float4*)(Vg + c * T_ + (s4 << 2));
        ushort4 hv = make_ushort4(f2bf(vv.x), f2bf(vv.y), f2bf(vv.z), f2bf(vv.w));
        *(ushort4*)(smem + VT_OFF + c * 80 + (s4 << 3)) = hv;
    }

    for (int it = 0; it < NITER; ++it) {
        __syncthreads();
        const int cur = it & 1;
        if (it + 1 < NITER) {
            const int nb = cur ^ 1;
            const int s0 = (it + 1) << 5;
            #pragma unroll
            for (int j = 0; j < 2; ++j) {
                int c = (tid >> 3) + (j << 6);
                float4 kv = *(const float4*)(Kg + c * T_ + s0 + (s4 << 2));
                #pragma unroll
                for (int jj = 0; jj < 4; ++jj) {
                    int srow = (s4 << 2) + jj;
                    *(unsigned short*)(smem + KT_OFF + (nb << 13) +
                        (((srow << 8) + (c << 1)) ^ ((srow & 7) << 4))) = f2bf((&kv.x)[jj]);
                }
                float4 vv = *(const float4*)(Vg + c * T_ + s0 + (s4 << 2));
                ushort4 hv = make_ushort4(f2bf(vv.x), f2bf(vv.y), f2bf(vv.z), f2bf(vv.w));
                *(ushort4*)(smem + VT_OFF + nb * 10240 + c * 80 + (s4 << 3)) = hv;
            }
        }

        // L[sn][ot]: logits[s = sn*16 + g*4 + r][o = wo + ot*16 + ln]  (swapped mfma)
        f32x4 L[2][2];
        L[0][0] = f32x4{0,0,0,0}; L[0][1] = f32x4{0,0,0,0};
        L[1][0] = f32x4{0,0,0,0}; L[1][1] = f32x4{0,0,0,0};
        #pragma unroll
        for (int kk = 0; kk < 4; ++kk) {
            int s0r = ln, s1r = 16 + ln;
            bf16x8 ak0 = *(const bf16x8*)(smem + KT_OFF + (cur << 13) +
                (((s0r << 8) + (kk << 6) + (g << 4)) ^ ((s0r & 7) << 4)));
            bf16x8 ak1 = *(const bf16x8*)(smem + KT_OFF + (cur << 13) +
                (((s1r << 8) + (kk << 6) + (g << 4)) ^ ((s1r & 7) << 4)));
            int o0r = wo + ln, o1r = wo + 16 + ln;
            bf16x8 bq0 = *(const bf16x8*)(smem + QT_OFF +
                (((o0r << 8) + (kk << 6) + (g << 4)) ^ ((o0r & 7) << 4)));
            bf16x8 bq1 = *(const bf16x8*)(smem + QT_OFF +
                (((o1r << 8) + (kk << 6) + (g << 4)) ^ ((o1r & 7) << 4)));
            L[0][0] = __builtin_amdgcn_mfma_f32_16x16x32_bf16(ak0, bq0, L[0][0], 0, 0, 0);
            L[0][1] = __builtin_amdgcn_mfma_f32_16x16x32_bf16(ak0, bq1, L[0][1], 0, 0, 0);
            L[1][0] = __builtin_amdgcn_mfma_f32_16x16x32_bf16(ak1, bq0, L[1][0], 0, 0, 0);
            L[1][1] = __builtin_amdgcn_mfma_f32_16x16x32_bf16(ak1, bq1, L[1][1], 0, 0, 0);
        }

        // online softmax per o-col (lane-local + 2 shfls)
        float alpha[2];
        #pragma unroll
        for (int ot = 0; ot < 2; ++ot) {
            float mx = fmaxf(fmaxf(fmaxf(L[0][ot][0], L[0][ot][1]), fmaxf(L[0][ot][2], L[0][ot][3])),
                             fmaxf(fmaxf(L[1][ot][0], L[1][ot][1]), fmaxf(L[1][ot][2], L[1][ot][3])));
            mx = fmaxf(mx, __shfl_xor(mx, 16, 64));
            mx = fmaxf(mx, __shfl_xor(mx, 32, 64));
            float mnew = fmaxf(m_run[ot], mx);
            float a0 = exp2f((m_run[ot] - mnew) * LOG2E);
            float ts = 0.f;
            ushort4 pw[2];
            #pragma unroll
            for (int sn = 0; sn < 2; ++sn) {
                float p0 = exp2f((L[sn][ot][0] - mnew) * LOG2E);
                float p1 = exp2f((L[sn][ot][1] - mnew) * LOG2E);
                float p2 = exp2f((L[sn][ot][2] - mnew) * LOG2E);
                float p3 = exp2f((L[sn][ot][3] - mnew) * LOG2E);
                ts += (p0 + p1) + (p2 + p3);
                pw[sn] = make_ushort4(f2bf(p0), f2bf(p1), f2bf(p2), f2bf(p3));
            }
            ts += __shfl_xor(ts, 16, 64);
            ts += __shfl_xor(ts, 32, 64);
            l_run[ot] = l_run[ot] * a0 + ts;
            m_run[ot] = mnew;
            alpha[ot] = a0;
            // P[o][s]: lane owns row o = wo + ot*16 + ln, writes s = sn*16 + g*4 + 0..3
            char* pr = smem + P_OFF + (wo + (ot << 4) + ln) * 80;
            *(ushort4*)(pr + ((g << 2) << 1))        = pw[0];
            *(ushort4*)(pr + ((16 + (g << 2)) << 1)) = pw[1];
        }

        // rescale + PV: acc[c][o] += V[c][s] * P[o][s]
        #pragma unroll
        for (int ct = 0; ct < 8; ++ct) {
            #pragma unroll
            for (int ot = 0; ot < 2; ++ot) {
                acc[ct][ot][0] *= alpha[ot]; acc[ct][ot][1] *= alpha[ot];
                acc[ct][ot][2] *= alpha[ot]; acc[ct][ot][3] *= alpha[ot];
            }
        }
        bf16x8 pf0 = *(const bf16x8*)(smem + P_OFF + (wo + ln) * 80 + (g << 4));
        bf16x8 pf1 = *(const bf16x8*)(smem + P_OFF + (wo + 16 + ln) * 80 + (g << 4));
        #pragma unroll
        for (int ct = 0; ct < 8; ++ct) {
            int c = (ct << 4) + ln;
            bf16x8 vf = *(const bf16x8*)(smem + VT_OFF + cur * 10240 + c * 80 + (g << 4));
            acc[ct][0] = __builtin_amdgcn_mfma_f32_16x16x32_bf16(vf, pf0, acc[ct][0], 0, 0, 0);
            acc[ct][1] = __builtin_amdgcn_mfma_f32_16x16x32_bf16(vf, pf1, acc[ct][1], 0, 0, 0);
        }
    }

    // ================= epilogue: out[b][h*128 + c][o] = acc / l =================
    {
        float linv0 = 1.0f / l_run[0], linv1 = 1.0f / l_run[1];
        float* ob = out + ((size_t)b * 1024 + h * 128) * 256;
        #pragma unroll
        for (int ct = 0; ct < 8; ++ct) {
            #pragma unroll
            for (int r = 0; r < 4; ++r) {
                int c = (ct << 4) + (g << 2) + r;
                ob[(size_t)c * 256 + wo + ln]      = acc[ct][0][r] * linv0;
                ob[(size_t)c * 256 + wo + 16 + ln] = acc[ct][1][r] * linv1;
            }
        }
    }
}

} // namespace

extern "C" void kernel_launch(void* const* d_in, const int* in_sizes, int n_in,
                              void* d_out, int out_size, void* d_ws, size_t ws_size,
                              hipStream_t stream) {
    const float* qkv = (const float*)d_in[0];
    const float* wq  = (const float*)d_in[1];
    const float* bq  = (const float*)d_in[2];
    float* out = (float*)d_out;
    hipLaunchKernelGGL(qkv_attn_kernel, dim3(256), dim3(512), 0, stream,
                       qkv, wq, bq, out);
}